// Round 7
// baseline (144.864 us; speedup 1.0000x reference)
//
#include <hip/hip_runtime.h>

#define DDIM 128

// Stage A: stream x, compute per-sample ||x - a_y||^2 via 16-lane groups
// (2 samples per group per iteration for MLP), accumulate per-class sums/counts
// in LDS, flush per-block partials (no global atomics).  [R4 structure — best measured]
__global__ __launch_bounds__(256) void dist_kernel(
    const float* __restrict__ x, const float* __restrict__ anchors,
    const int* __restrict__ y,
    float* __restrict__ pseg, unsigned* __restrict__ pcnt,
    int n, int C)
{
    extern __shared__ char smem[];
    float*    segL = (float*)smem;
    unsigned* cntL = (unsigned*)(smem + (size_t)C * sizeof(float));

    for (int c = threadIdx.x; c < C; c += blockDim.x) { segL[c] = 0.0f; cntL[c] = 0u; }
    __syncthreads();

    const int tid  = blockIdx.x * blockDim.x + threadIdx.x;
    const int wave = tid >> 6;
    const int lane = threadIdx.x & 63;
    const int g    = lane >> 4;   // sample group within wave (0..3)
    const int q    = lane & 15;   // lane within 16-lane group
    const int totalWaves = (gridDim.x * blockDim.x) >> 6;
    const int stride = totalWaves * 8;          // 8 samples per wave per iter

    for (int base = wave * 8; base < n; base += stride) {
        const int i0 = base + g;        // sample A for this group
        const int i1 = i0 + 4;          // sample B for this group
        const bool v0 = i0 < n, v1 = i1 < n;

        int l0 = 0, l1 = 0;
        if (v0) l0 = y[i0];
        if (v1) l1 = y[i1];

        float4 xa0, xa1, xb0, xb1;
        float4 aa0, aa1, ab0, ab1;
        if (v0) {
            const float4* xp = (const float4*)(x + (size_t)i0 * DDIM + q * 8);
            xa0 = xp[0]; xa1 = xp[1];
        }
        if (v1) {
            const float4* xp = (const float4*)(x + (size_t)i1 * DDIM + q * 8);
            xb0 = xp[0]; xb1 = xp[1];
        }
        if (v0) {
            const float4* ap = (const float4*)(anchors + (size_t)l0 * DDIM + q * 8);
            aa0 = ap[0]; aa1 = ap[1];
        }
        if (v1) {
            const float4* ap = (const float4*)(anchors + (size_t)l1 * DDIM + q * 8);
            ab0 = ap[0]; ab1 = ap[1];
        }

        float acc0 = 0.0f, acc1 = 0.0f;
        if (v0) {
            float d;
            d = xa0.x - aa0.x; acc0 = fmaf(d, d, acc0);
            d = xa0.y - aa0.y; acc0 = fmaf(d, d, acc0);
            d = xa0.z - aa0.z; acc0 = fmaf(d, d, acc0);
            d = xa0.w - aa0.w; acc0 = fmaf(d, d, acc0);
            d = xa1.x - aa1.x; acc0 = fmaf(d, d, acc0);
            d = xa1.y - aa1.y; acc0 = fmaf(d, d, acc0);
            d = xa1.z - aa1.z; acc0 = fmaf(d, d, acc0);
            d = xa1.w - aa1.w; acc0 = fmaf(d, d, acc0);
        }
        if (v1) {
            float d;
            d = xb0.x - ab0.x; acc1 = fmaf(d, d, acc1);
            d = xb0.y - ab0.y; acc1 = fmaf(d, d, acc1);
            d = xb0.z - ab0.z; acc1 = fmaf(d, d, acc1);
            d = xb0.w - ab0.w; acc1 = fmaf(d, d, acc1);
            d = xb1.x - ab1.x; acc1 = fmaf(d, d, acc1);
            d = xb1.y - ab1.y; acc1 = fmaf(d, d, acc1);
            d = xb1.z - ab1.z; acc1 = fmaf(d, d, acc1);
            d = xb1.w - ab1.w; acc1 = fmaf(d, d, acc1);
        }

        #pragma unroll
        for (int off = 1; off < 16; off <<= 1) {
            acc0 += __shfl_xor(acc0, off);
            acc1 += __shfl_xor(acc1, off);
        }
        if (q == 0) {
            if (v0) { atomicAdd(&segL[l0], acc0); atomicAdd(&cntL[l0], 1u); }
            if (v1) { atomicAdd(&segL[l1], acc1); atomicAdd(&cntL[l1], 1u); }
        }
    }
    __syncthreads();

    float*    myseg = pseg + (size_t)blockIdx.x * C;
    unsigned* mycnt = pcnt + (size_t)blockIdx.x * C;
    for (int c = threadIdx.x; c < C; c += blockDim.x) {
        myseg[c] = segL[c];
        mycnt[c] = cntL[c];
    }
}

// Stage B (vectorized): thread handles 4 consecutive classes via float4/uint4,
// sums rowsPerSlice consecutive partial rows — coalesced 16B reads across threads.
__global__ __launch_bounds__(256) void reduceB4_kernel(
    const float4* __restrict__ pseg4, const uint4* __restrict__ pcnt4,
    float4* __restrict__ sseg4, float4* __restrict__ scnt4,
    int B, int C4, int rowsPerSlice)
{
    const int c4 = blockIdx.x * 256 + threadIdx.x;
    if (c4 >= C4) return;
    const int slice = blockIdx.y;
    const int b0 = slice * rowsPerSlice;
    int b1 = b0 + rowsPerSlice; if (b1 > B) b1 = B;

    float4 s = {0.f, 0.f, 0.f, 0.f};
    float4 k = {0.f, 0.f, 0.f, 0.f};
    for (int b = b0; b < b1; ++b) {
        float4 ps = pseg4[(size_t)b * C4 + c4];
        uint4  pc = pcnt4[(size_t)b * C4 + c4];
        s.x += ps.x; s.y += ps.y; s.z += ps.z; s.w += ps.w;
        k.x += (float)pc.x; k.y += (float)pc.y; k.z += (float)pc.z; k.w += (float)pc.w;
    }
    sseg4[(size_t)slice * C4 + c4] = s;
    scnt4[(size_t)slice * C4 + c4] = k;
}

// Stage B (scalar fallback for C % 4 != 0).
__global__ __launch_bounds__(256) void reduceB_kernel(
    const float* __restrict__ pseg, const unsigned* __restrict__ pcnt,
    float* __restrict__ sseg, float* __restrict__ scnt,
    int B, int C, int rowsPerSlice)
{
    const int c = blockIdx.x * 256 + threadIdx.x;
    if (c >= C) return;
    const int slice = blockIdx.y;
    const int b0 = slice * rowsPerSlice;
    int b1 = b0 + rowsPerSlice; if (b1 > B) b1 = B;

    float s = 0.0f, k = 0.0f;
    for (int b = b0; b < b1; ++b) {
        s += pseg[(size_t)b * C + c];
        k += (float)pcnt[(size_t)b * C + c];
    }
    sseg[(size_t)slice * C + c] = s;
    scnt[(size_t)slice * C + c] = k;
}

// Stage C: one block; thread per class sums slice partials (coalesced),
// applies s/k^2, block-reduces to out[0].
__global__ __launch_bounds__(1024) void finalize_kernel(
    const float* __restrict__ sseg, const float* __restrict__ scnt,
    float* __restrict__ out, int nslice, int C)
{
    __shared__ float red[1024];
    const int t = threadIdx.x;
    float v = 0.0f;
    for (int c = t; c < C; c += 1024) {
        float s = 0.0f, k = 0.0f;
        for (int sl = 0; sl < nslice; ++sl) {
            s += sseg[(size_t)sl * C + c];
            k += scnt[(size_t)sl * C + c];
        }
        if (k > 0.0f) v += s / (k * k);
    }
    red[t] = v;
    __syncthreads();
    #pragma unroll
    for (int st = 512; st > 0; st >>= 1) {
        if (t < st) red[t] += red[t + st];
        __syncthreads();
    }
    if (t == 0) out[0] = red[0];
}

extern "C" void kernel_launch(void* const* d_in, const int* in_sizes, int n_in,
                              void* d_out, int out_size, void* d_ws, size_t ws_size,
                              hipStream_t stream) {
    const float* x       = (const float*)d_in[0];
    const float* anchors = (const float*)d_in[1];
    const int*   y       = (const int*)d_in[2];
    float*       out     = (float*)d_out;

    const int n = in_sizes[2];          // N samples
    const int C = in_sizes[1] / DDIM;   // classes

    const int rowsPerSlice = 64;

    // B = 1024 blocks (4/CU, 16 waves/CU): halves tail imbalance (30.5 iters/wave
    // vs 15.3) and halves the partial matrix that stage B must re-read.
    long long cap = ((long long)ws_size) / ((long long)C * 8 + (long long)C * 16 / rowsPerSlice + 16);
    int B = (int)(cap < 1 ? 1 : (cap > 1024 ? 1024 : cap));
    const int nslice = (B + rowsPerSlice - 1) / rowsPerSlice;

    float*    pseg = (float*)d_ws;
    unsigned* pcnt = (unsigned*)((char*)d_ws + (size_t)B * C * 4);
    float*    sseg = (float*)((char*)d_ws + (size_t)B * C * 8);
    float*    scnt = (float*)((char*)d_ws + (size_t)B * C * 8 + (size_t)nslice * C * 4);

    const size_t ldsBytes = (size_t)C * 8;  // segL + cntL
    dist_kernel<<<B, 256, ldsBytes, stream>>>(x, anchors, y, pseg, pcnt, n, C);

    if ((C & 3) == 0) {
        const int C4 = C >> 2;
        dim3 gridB((C4 + 255) / 256, nslice);
        reduceB4_kernel<<<gridB, 256, 0, stream>>>(
            (const float4*)pseg, (const uint4*)pcnt,
            (float4*)sseg, (float4*)scnt, B, C4, rowsPerSlice);
    } else {
        dim3 gridB((C + 255) / 256, nslice);
        reduceB_kernel<<<gridB, 256, 0, stream>>>(pseg, pcnt, sseg, scnt, B, C, rowsPerSlice);
    }

    finalize_kernel<<<1, 1024, 0, stream>>>(sseg, scnt, out, nslice, C);
}

// Round 8
// 136.099 us; speedup vs baseline: 1.0644x; 1.0644x over previous
//
#include <hip/hip_runtime.h>

#define DDIM 128   // floats per row = 32 float4

// Stage A: flat half-wave layout. Each half-wave (32 lanes) owns one row per
// load: lane reads float4 #(row*32 + (lane&31)) — fully dense, contiguous
// 512B per half-wave, zero wasted cache-line bytes. Per wave-iter: 4 rows
// (2 x-loads + 2 anchor-loads per lane). 5-step shfl_xor reduce per half-wave,
// LDS histogram, per-block partial flush. B=2048 → 8 blocks/CU (R7 showed
// occupancy below this regresses hard).
__global__ __launch_bounds__(256) void dist_kernel(
    const float* __restrict__ x, const float* __restrict__ anchors,
    const int* __restrict__ y,
    float* __restrict__ pseg, unsigned* __restrict__ pcnt,
    int n, int C)
{
    extern __shared__ char smem[];
    float*    segL = (float*)smem;
    unsigned* cntL = (unsigned*)(smem + (size_t)C * sizeof(float));

    for (int c = threadIdx.x; c < C; c += blockDim.x) { segL[c] = 0.0f; cntL[c] = 0u; }
    __syncthreads();

    const int tid  = blockIdx.x * blockDim.x + threadIdx.x;
    const int wave = tid >> 6;
    const int lane = threadIdx.x & 63;
    const int half = lane >> 5;   // 0: rows R,R+2 ; 1: rows R+1,R+3
    const int c4   = lane & 31;   // float4 chunk within row
    const int totalWaves = (gridDim.x * blockDim.x) >> 6;
    const int rowStride = totalWaves * 4;     // 4 rows per wave per iter

    const float4* x4 = (const float4*)x;
    const float4* a4 = (const float4*)anchors;

    int R = wave * 4;
    for (; R + 4 <= n; R += rowStride) {
        const int rA = R + half;          // rows R, R+1
        const int rB = rA + 2;            // rows R+2, R+3

        const int lA = y[rA];             // broadcast within half-wave
        const int lB = y[rB];

        float4 xa = x4[rA * 32 + c4];     // wave: 1KB contiguous
        float4 xb = x4[rB * 32 + c4];
        float4 aa = a4[lA * 32 + c4];     // half-wave: full 512B anchor row
        float4 ab = a4[lB * 32 + c4];

        float acc0 = 0.0f, acc1 = 0.0f, d;
        d = xa.x - aa.x; acc0 = fmaf(d, d, acc0);
        d = xa.y - aa.y; acc0 = fmaf(d, d, acc0);
        d = xa.z - aa.z; acc0 = fmaf(d, d, acc0);
        d = xa.w - aa.w; acc0 = fmaf(d, d, acc0);
        d = xb.x - ab.x; acc1 = fmaf(d, d, acc1);
        d = xb.y - ab.y; acc1 = fmaf(d, d, acc1);
        d = xb.z - ab.z; acc1 = fmaf(d, d, acc1);
        d = xb.w - ab.w; acc1 = fmaf(d, d, acc1);

        // reduce over the 32 lanes of each half-wave (xor offsets <32 stay in-half)
        #pragma unroll
        for (int off = 1; off < 32; off <<= 1) {
            acc0 += __shfl_xor(acc0, off);
            acc1 += __shfl_xor(acc1, off);
        }
        if (c4 == 0) {
            atomicAdd(&segL[lA], acc0); atomicAdd(&cntL[lA], 1u);
            atomicAdd(&segL[lB], acc1); atomicAdd(&cntL[lB], 1u);
        }
    }

    // Tail: at most one wave straddles n (only taken if n % 4 != 0).
    if (R < n) {
        const int rA = R + half;
        const int rB = rA + 2;
        const bool vA = rA < n, vB = rB < n;
        int lA = 0, lB = 0;
        if (vA) lA = y[rA];
        if (vB) lB = y[rB];

        float acc0 = 0.0f, acc1 = 0.0f, d;
        if (vA) {
            float4 xa = x4[rA * 32 + c4];
            float4 aa = a4[lA * 32 + c4];
            d = xa.x - aa.x; acc0 = fmaf(d, d, acc0);
            d = xa.y - aa.y; acc0 = fmaf(d, d, acc0);
            d = xa.z - aa.z; acc0 = fmaf(d, d, acc0);
            d = xa.w - aa.w; acc0 = fmaf(d, d, acc0);
        }
        if (vB) {
            float4 xb = x4[rB * 32 + c4];
            float4 ab = a4[lB * 32 + c4];
            d = xb.x - ab.x; acc1 = fmaf(d, d, acc1);
            d = xb.y - ab.y; acc1 = fmaf(d, d, acc1);
            d = xb.z - ab.z; acc1 = fmaf(d, d, acc1);
            d = xb.w - ab.w; acc1 = fmaf(d, d, acc1);
        }
        #pragma unroll
        for (int off = 1; off < 32; off <<= 1) {
            acc0 += __shfl_xor(acc0, off);
            acc1 += __shfl_xor(acc1, off);
        }
        if (c4 == 0) {
            if (vA) { atomicAdd(&segL[lA], acc0); atomicAdd(&cntL[lA], 1u); }
            if (vB) { atomicAdd(&segL[lB], acc1); atomicAdd(&cntL[lB], 1u); }
        }
    }
    __syncthreads();

    float*    myseg = pseg + (size_t)blockIdx.x * C;
    unsigned* mycnt = pcnt + (size_t)blockIdx.x * C;
    for (int c = threadIdx.x; c < C; c += blockDim.x) {
        myseg[c] = segL[c];
        mycnt[c] = cntL[c];
    }
}

// Stage B (vectorized): thread handles 4 consecutive classes via float4/uint4,
// sums rowsPerSlice consecutive partial rows — coalesced 16B reads.
__global__ __launch_bounds__(256) void reduceB4_kernel(
    const float4* __restrict__ pseg4, const uint4* __restrict__ pcnt4,
    float4* __restrict__ sseg4, float4* __restrict__ scnt4,
    int B, int C4, int rowsPerSlice)
{
    const int c4 = blockIdx.x * 256 + threadIdx.x;
    if (c4 >= C4) return;
    const int slice = blockIdx.y;
    const int b0 = slice * rowsPerSlice;
    int b1 = b0 + rowsPerSlice; if (b1 > B) b1 = B;

    float4 s = {0.f, 0.f, 0.f, 0.f};
    float4 k = {0.f, 0.f, 0.f, 0.f};
    for (int b = b0; b < b1; ++b) {
        float4 ps = pseg4[(size_t)b * C4 + c4];
        uint4  pc = pcnt4[(size_t)b * C4 + c4];
        s.x += ps.x; s.y += ps.y; s.z += ps.z; s.w += ps.w;
        k.x += (float)pc.x; k.y += (float)pc.y; k.z += (float)pc.z; k.w += (float)pc.w;
    }
    sseg4[(size_t)slice * C4 + c4] = s;
    scnt4[(size_t)slice * C4 + c4] = k;
}

// Stage B (scalar fallback for C % 4 != 0).
__global__ __launch_bounds__(256) void reduceB_kernel(
    const float* __restrict__ pseg, const unsigned* __restrict__ pcnt,
    float* __restrict__ sseg, float* __restrict__ scnt,
    int B, int C, int rowsPerSlice)
{
    const int c = blockIdx.x * 256 + threadIdx.x;
    if (c >= C) return;
    const int slice = blockIdx.y;
    const int b0 = slice * rowsPerSlice;
    int b1 = b0 + rowsPerSlice; if (b1 > B) b1 = B;

    float s = 0.0f, k = 0.0f;
    for (int b = b0; b < b1; ++b) {
        s += pseg[(size_t)b * C + c];
        k += (float)pcnt[(size_t)b * C + c];
    }
    sseg[(size_t)slice * C + c] = s;
    scnt[(size_t)slice * C + c] = k;
}

// Stage C: one block; thread per class sums slice partials (coalesced),
// applies s/k^2, block-reduces to out[0].
__global__ __launch_bounds__(1024) void finalize_kernel(
    const float* __restrict__ sseg, const float* __restrict__ scnt,
    float* __restrict__ out, int nslice, int C)
{
    __shared__ float red[1024];
    const int t = threadIdx.x;
    float v = 0.0f;
    for (int c = t; c < C; c += 1024) {
        float s = 0.0f, k = 0.0f;
        for (int sl = 0; sl < nslice; ++sl) {
            s += sseg[(size_t)sl * C + c];
            k += scnt[(size_t)sl * C + c];
        }
        if (k > 0.0f) v += s / (k * k);
    }
    red[t] = v;
    __syncthreads();
    #pragma unroll
    for (int st = 512; st > 0; st >>= 1) {
        if (t < st) red[t] += red[t + st];
        __syncthreads();
    }
    if (t == 0) out[0] = red[0];
}

extern "C" void kernel_launch(void* const* d_in, const int* in_sizes, int n_in,
                              void* d_out, int out_size, void* d_ws, size_t ws_size,
                              hipStream_t stream) {
    const float* x       = (const float*)d_in[0];
    const float* anchors = (const float*)d_in[1];
    const int*   y       = (const int*)d_in[2];
    float*       out     = (float*)d_out;

    const int n = in_sizes[2];          // N samples
    const int C = in_sizes[1] / DDIM;   // classes

    const int rowsPerSlice = 64;

    // B = 2048: 8 blocks/CU, full 2048-thread occupancy (R7: anything less regresses).
    long long cap = ((long long)ws_size) / ((long long)C * 8 + (long long)C * 16 / rowsPerSlice + 16);
    int B = (int)(cap < 1 ? 1 : (cap > 2048 ? 2048 : cap));
    const int nslice = (B + rowsPerSlice - 1) / rowsPerSlice;

    float*    pseg = (float*)d_ws;
    unsigned* pcnt = (unsigned*)((char*)d_ws + (size_t)B * C * 4);
    float*    sseg = (float*)((char*)d_ws + (size_t)B * C * 8);
    float*    scnt = (float*)((char*)d_ws + (size_t)B * C * 8 + (size_t)nslice * C * 4);

    const size_t ldsBytes = (size_t)C * 8;  // segL + cntL
    dist_kernel<<<B, 256, ldsBytes, stream>>>(x, anchors, y, pseg, pcnt, n, C);

    if ((C & 3) == 0) {
        const int C4 = C >> 2;
        dim3 gridB((C4 + 255) / 256, nslice);
        reduceB4_kernel<<<gridB, 256, 0, stream>>>(
            (const float4*)pseg, (const uint4*)pcnt,
            (float4*)sseg, (float4*)scnt, B, C4, rowsPerSlice);
    } else {
        dim3 gridB((C + 255) / 256, nslice);
        reduceB_kernel<<<gridB, 256, 0, stream>>>(pseg, pcnt, sseg, scnt, B, C, rowsPerSlice);
    }

    finalize_kernel<<<1, 1024, 0, stream>>>(sseg, scnt, out, nslice, C);
}

// Round 9
// 129.718 us; speedup vs baseline: 1.1168x; 1.0492x over previous
//
#include <hip/hip_runtime.h>

#define DDIM 128

// Stage A: R4's exact wave-level body (best measured), but 1024-thread blocks:
// B=512 blocks -> 2 blocks/CU, 32 waves/CU (full occupancy), 4x fewer LDS
// histogram copies -> partial matrix 16MB -> 4MB. Same 8192 waves, same
// per-wave iteration structure as R4.
__global__ __launch_bounds__(1024, 8) void dist_kernel(
    const float* __restrict__ x, const float* __restrict__ anchors,
    const int* __restrict__ y,
    float* __restrict__ pseg, unsigned* __restrict__ pcnt,
    int n, int C)
{
    extern __shared__ char smem[];
    float*    segL = (float*)smem;
    unsigned* cntL = (unsigned*)(smem + (size_t)C * sizeof(float));

    for (int c = threadIdx.x; c < C; c += blockDim.x) { segL[c] = 0.0f; cntL[c] = 0u; }
    __syncthreads();

    const int tid  = blockIdx.x * blockDim.x + threadIdx.x;
    const int wave = tid >> 6;
    const int lane = threadIdx.x & 63;
    const int g    = lane >> 4;   // sample group within wave (0..3)
    const int q    = lane & 15;   // lane within 16-lane group
    const int totalWaves = (gridDim.x * blockDim.x) >> 6;
    const int stride = totalWaves * 8;          // 8 samples per wave per iter

    for (int base = wave * 8; base < n; base += stride) {
        const int i0 = base + g;        // sample A for this group
        const int i1 = i0 + 4;          // sample B for this group
        const bool v0 = i0 < n, v1 = i1 < n;

        int l0 = 0, l1 = 0;
        if (v0) l0 = y[i0];
        if (v1) l1 = y[i1];

        float4 xa0, xa1, xb0, xb1;
        float4 aa0, aa1, ab0, ab1;
        if (v0) {
            const float4* xp = (const float4*)(x + (size_t)i0 * DDIM + q * 8);
            xa0 = xp[0]; xa1 = xp[1];
        }
        if (v1) {
            const float4* xp = (const float4*)(x + (size_t)i1 * DDIM + q * 8);
            xb0 = xp[0]; xb1 = xp[1];
        }
        if (v0) {
            const float4* ap = (const float4*)(anchors + (size_t)l0 * DDIM + q * 8);
            aa0 = ap[0]; aa1 = ap[1];
        }
        if (v1) {
            const float4* ap = (const float4*)(anchors + (size_t)l1 * DDIM + q * 8);
            ab0 = ap[0]; ab1 = ap[1];
        }

        float acc0 = 0.0f, acc1 = 0.0f;
        if (v0) {
            float d;
            d = xa0.x - aa0.x; acc0 = fmaf(d, d, acc0);
            d = xa0.y - aa0.y; acc0 = fmaf(d, d, acc0);
            d = xa0.z - aa0.z; acc0 = fmaf(d, d, acc0);
            d = xa0.w - aa0.w; acc0 = fmaf(d, d, acc0);
            d = xa1.x - aa1.x; acc0 = fmaf(d, d, acc0);
            d = xa1.y - aa1.y; acc0 = fmaf(d, d, acc0);
            d = xa1.z - aa1.z; acc0 = fmaf(d, d, acc0);
            d = xa1.w - aa1.w; acc0 = fmaf(d, d, acc0);
        }
        if (v1) {
            float d;
            d = xb0.x - ab0.x; acc1 = fmaf(d, d, acc1);
            d = xb0.y - ab0.y; acc1 = fmaf(d, d, acc1);
            d = xb0.z - ab0.z; acc1 = fmaf(d, d, acc1);
            d = xb0.w - ab0.w; acc1 = fmaf(d, d, acc1);
            d = xb1.x - ab1.x; acc1 = fmaf(d, d, acc1);
            d = xb1.y - ab1.y; acc1 = fmaf(d, d, acc1);
            d = xb1.z - ab1.z; acc1 = fmaf(d, d, acc1);
            d = xb1.w - ab1.w; acc1 = fmaf(d, d, acc1);
        }

        #pragma unroll
        for (int off = 1; off < 16; off <<= 1) {
            acc0 += __shfl_xor(acc0, off);
            acc1 += __shfl_xor(acc1, off);
        }
        if (q == 0) {
            if (v0) { atomicAdd(&segL[l0], acc0); atomicAdd(&cntL[l0], 1u); }
            if (v1) { atomicAdd(&segL[l1], acc1); atomicAdd(&cntL[l1], 1u); }
        }
    }
    __syncthreads();

    float*    myseg = pseg + (size_t)blockIdx.x * C;
    unsigned* mycnt = pcnt + (size_t)blockIdx.x * C;
    for (int c = threadIdx.x; c < C; c += blockDim.x) {
        myseg[c] = segL[c];
        mycnt[c] = cntL[c];
    }
}

// Stage B (vectorized): thread handles 4 consecutive classes via float4/uint4,
// sums rowsPerSlice consecutive partial rows — coalesced 16B reads.
__global__ __launch_bounds__(256) void reduceB4_kernel(
    const float4* __restrict__ pseg4, const uint4* __restrict__ pcnt4,
    float4* __restrict__ sseg4, float4* __restrict__ scnt4,
    int B, int C4, int rowsPerSlice)
{
    const int c4 = blockIdx.x * 256 + threadIdx.x;
    if (c4 >= C4) return;
    const int slice = blockIdx.y;
    const int b0 = slice * rowsPerSlice;
    int b1 = b0 + rowsPerSlice; if (b1 > B) b1 = B;

    float4 s = {0.f, 0.f, 0.f, 0.f};
    float4 k = {0.f, 0.f, 0.f, 0.f};
    for (int b = b0; b < b1; ++b) {
        float4 ps = pseg4[(size_t)b * C4 + c4];
        uint4  pc = pcnt4[(size_t)b * C4 + c4];
        s.x += ps.x; s.y += ps.y; s.z += ps.z; s.w += ps.w;
        k.x += (float)pc.x; k.y += (float)pc.y; k.z += (float)pc.z; k.w += (float)pc.w;
    }
    sseg4[(size_t)slice * C4 + c4] = s;
    scnt4[(size_t)slice * C4 + c4] = k;
}

// Stage B (scalar fallback for C % 4 != 0).
__global__ __launch_bounds__(256) void reduceB_kernel(
    const float* __restrict__ pseg, const unsigned* __restrict__ pcnt,
    float* __restrict__ sseg, float* __restrict__ scnt,
    int B, int C, int rowsPerSlice)
{
    const int c = blockIdx.x * 256 + threadIdx.x;
    if (c >= C) return;
    const int slice = blockIdx.y;
    const int b0 = slice * rowsPerSlice;
    int b1 = b0 + rowsPerSlice; if (b1 > B) b1 = B;

    float s = 0.0f, k = 0.0f;
    for (int b = b0; b < b1; ++b) {
        s += pseg[(size_t)b * C + c];
        k += (float)pcnt[(size_t)b * C + c];
    }
    sseg[(size_t)slice * C + c] = s;
    scnt[(size_t)slice * C + c] = k;
}

// Stage C: one block; thread per class sums slice partials (coalesced),
// applies s/k^2, block-reduces to out[0].
__global__ __launch_bounds__(1024) void finalize_kernel(
    const float* __restrict__ sseg, const float* __restrict__ scnt,
    float* __restrict__ out, int nslice, int C)
{
    __shared__ float red[1024];
    const int t = threadIdx.x;
    float v = 0.0f;
    for (int c = t; c < C; c += 1024) {
        float s = 0.0f, k = 0.0f;
        for (int sl = 0; sl < nslice; ++sl) {
            s += sseg[(size_t)sl * C + c];
            k += scnt[(size_t)sl * C + c];
        }
        if (k > 0.0f) v += s / (k * k);
    }
    red[t] = v;
    __syncthreads();
    #pragma unroll
    for (int st = 512; st > 0; st >>= 1) {
        if (t < st) red[t] += red[t + st];
        __syncthreads();
    }
    if (t == 0) out[0] = red[0];
}

extern "C" void kernel_launch(void* const* d_in, const int* in_sizes, int n_in,
                              void* d_out, int out_size, void* d_ws, size_t ws_size,
                              hipStream_t stream) {
    const float* x       = (const float*)d_in[0];
    const float* anchors = (const float*)d_in[1];
    const int*   y       = (const int*)d_in[2];
    float*       out     = (float*)d_out;

    const int n = in_sizes[2];          // N samples
    const int C = in_sizes[1] / DDIM;   // classes

    const int rowsPerSlice = 64;

    // B = 512 blocks of 1024 threads: 2 blocks/CU, 32 waves/CU (same total
    // wave count & per-wave work as R4's best), partial matrix 4x smaller.
    long long cap = ((long long)ws_size) / ((long long)C * 8 + (long long)C * 16 / rowsPerSlice + 16);
    int B = (int)(cap < 1 ? 1 : (cap > 512 ? 512 : cap));
    const int nslice = (B + rowsPerSlice - 1) / rowsPerSlice;

    float*    pseg = (float*)d_ws;
    unsigned* pcnt = (unsigned*)((char*)d_ws + (size_t)B * C * 4);
    float*    sseg = (float*)((char*)d_ws + (size_t)B * C * 8);
    float*    scnt = (float*)((char*)d_ws + (size_t)B * C * 8 + (size_t)nslice * C * 4);

    const size_t ldsBytes = (size_t)C * 8;  // segL + cntL
    dist_kernel<<<B, 1024, ldsBytes, stream>>>(x, anchors, y, pseg, pcnt, n, C);

    if ((C & 3) == 0) {
        const int C4 = C >> 2;
        dim3 gridB((C4 + 255) / 256, nslice);
        reduceB4_kernel<<<gridB, 256, 0, stream>>>(
            (const float4*)pseg, (const uint4*)pcnt,
            (float4*)sseg, (float4*)scnt, B, C4, rowsPerSlice);
    } else {
        dim3 gridB((C + 255) / 256, nslice);
        reduceB_kernel<<<gridB, 256, 0, stream>>>(pseg, pcnt, sseg, scnt, B, C, rowsPerSlice);
    }

    finalize_kernel<<<1, 1024, 0, stream>>>(sseg, scnt, out, nslice, C);
}

// Round 10
// 118.318 us; speedup vs baseline: 1.2244x; 1.0963x over previous
//
#include <hip/hip_runtime.h>

#define DDIM 128

// Stage A: stream x, compute per-sample ||x - a_y||^2.
// [R4 configuration — best measured: 118.5 µs. All 5 structural perturbations
//  (R5 label-pipelining, R6 branch-free, R7 quarter-grid, R8 flat layout,
//  R9 fat blocks) regressed. 2048 blocks x 256 thr = 8 blocks/CU, 16-lane
//  groups, 2 samples/group/iter, LDS histogram, per-block partial flush.]
__global__ __launch_bounds__(256) void dist_kernel(
    const float* __restrict__ x, const float* __restrict__ anchors,
    const int* __restrict__ y,
    float* __restrict__ pseg, unsigned* __restrict__ pcnt,
    int n, int C)
{
    extern __shared__ char smem[];
    float*    segL = (float*)smem;
    unsigned* cntL = (unsigned*)(smem + (size_t)C * sizeof(float));

    for (int c = threadIdx.x; c < C; c += blockDim.x) { segL[c] = 0.0f; cntL[c] = 0u; }
    __syncthreads();

    const int tid  = blockIdx.x * blockDim.x + threadIdx.x;
    const int wave = tid >> 6;
    const int lane = threadIdx.x & 63;
    const int g    = lane >> 4;   // sample group within wave (0..3)
    const int q    = lane & 15;   // lane within 16-lane group
    const int totalWaves = (gridDim.x * blockDim.x) >> 6;
    const int stride = totalWaves * 8;          // 8 samples per wave per iter

    for (int base = wave * 8; base < n; base += stride) {
        const int i0 = base + g;        // sample A for this group
        const int i1 = i0 + 4;          // sample B for this group
        const bool v0 = i0 < n, v1 = i1 < n;

        int l0 = 0, l1 = 0;
        if (v0) l0 = y[i0];
        if (v1) l1 = y[i1];

        float4 xa0, xa1, xb0, xb1;
        float4 aa0, aa1, ab0, ab1;
        if (v0) {
            const float4* xp = (const float4*)(x + (size_t)i0 * DDIM + q * 8);
            xa0 = xp[0]; xa1 = xp[1];
        }
        if (v1) {
            const float4* xp = (const float4*)(x + (size_t)i1 * DDIM + q * 8);
            xb0 = xp[0]; xb1 = xp[1];
        }
        if (v0) {
            const float4* ap = (const float4*)(anchors + (size_t)l0 * DDIM + q * 8);
            aa0 = ap[0]; aa1 = ap[1];
        }
        if (v1) {
            const float4* ap = (const float4*)(anchors + (size_t)l1 * DDIM + q * 8);
            ab0 = ap[0]; ab1 = ap[1];
        }

        float acc0 = 0.0f, acc1 = 0.0f;
        if (v0) {
            float d;
            d = xa0.x - aa0.x; acc0 = fmaf(d, d, acc0);
            d = xa0.y - aa0.y; acc0 = fmaf(d, d, acc0);
            d = xa0.z - aa0.z; acc0 = fmaf(d, d, acc0);
            d = xa0.w - aa0.w; acc0 = fmaf(d, d, acc0);
            d = xa1.x - aa1.x; acc0 = fmaf(d, d, acc0);
            d = xa1.y - aa1.y; acc0 = fmaf(d, d, acc0);
            d = xa1.z - aa1.z; acc0 = fmaf(d, d, acc0);
            d = xa1.w - aa1.w; acc0 = fmaf(d, d, acc0);
        }
        if (v1) {
            float d;
            d = xb0.x - ab0.x; acc1 = fmaf(d, d, acc1);
            d = xb0.y - ab0.y; acc1 = fmaf(d, d, acc1);
            d = xb0.z - ab0.z; acc1 = fmaf(d, d, acc1);
            d = xb0.w - ab0.w; acc1 = fmaf(d, d, acc1);
            d = xb1.x - ab1.x; acc1 = fmaf(d, d, acc1);
            d = xb1.y - ab1.y; acc1 = fmaf(d, d, acc1);
            d = xb1.z - ab1.z; acc1 = fmaf(d, d, acc1);
            d = xb1.w - ab1.w; acc1 = fmaf(d, d, acc1);
        }

        #pragma unroll
        for (int off = 1; off < 16; off <<= 1) {
            acc0 += __shfl_xor(acc0, off);
            acc1 += __shfl_xor(acc1, off);
        }
        if (q == 0) {
            if (v0) { atomicAdd(&segL[l0], acc0); atomicAdd(&cntL[l0], 1u); }
            if (v1) { atomicAdd(&segL[l1], acc1); atomicAdd(&cntL[l1], 1u); }
        }
    }
    __syncthreads();

    float*    myseg = pseg + (size_t)blockIdx.x * C;
    unsigned* mycnt = pcnt + (size_t)blockIdx.x * C;
    for (int c = threadIdx.x; c < C; c += blockDim.x) {
        myseg[c] = segL[c];
        mycnt[c] = cntL[c];
    }
}

// Stage B: 2-D grid (class-chunk, b-slice). Thread t owns class chunk*256+t and
// sums rowsPerSlice consecutive partial rows — coalesced reads across threads.
__global__ __launch_bounds__(256) void reduceB_kernel(
    const float* __restrict__ pseg, const unsigned* __restrict__ pcnt,
    float* __restrict__ sseg, float* __restrict__ scnt,
    int B, int C, int rowsPerSlice)
{
    const int c = blockIdx.x * 256 + threadIdx.x;
    if (c >= C) return;
    const int slice = blockIdx.y;
    const int b0 = slice * rowsPerSlice;
    int b1 = b0 + rowsPerSlice; if (b1 > B) b1 = B;

    float s = 0.0f, k = 0.0f;
    #pragma unroll 8
    for (int b = b0; b < b1; ++b) {
        s += pseg[(size_t)b * C + c];
        k += (float)pcnt[(size_t)b * C + c];
    }
    sseg[(size_t)slice * C + c] = s;
    scnt[(size_t)slice * C + c] = k;
}

// Stage C: one block; thread per class sums slice partials (coalesced),
// applies s/k^2, block-reduces to out[0].
__global__ __launch_bounds__(1024) void finalize_kernel(
    const float* __restrict__ sseg, const float* __restrict__ scnt,
    float* __restrict__ out, int nslice, int C)
{
    __shared__ float red[1024];
    const int t = threadIdx.x;
    float v = 0.0f;
    for (int c = t; c < C; c += 1024) {
        float s = 0.0f, k = 0.0f;
        for (int sl = 0; sl < nslice; ++sl) {
            s += sseg[(size_t)sl * C + c];
            k += scnt[(size_t)sl * C + c];
        }
        if (k > 0.0f) v += s / (k * k);
    }
    red[t] = v;
    __syncthreads();
    #pragma unroll
    for (int st = 512; st > 0; st >>= 1) {
        if (t < st) red[t] += red[t + st];
        __syncthreads();
    }
    if (t == 0) out[0] = red[0];
}

extern "C" void kernel_launch(void* const* d_in, const int* in_sizes, int n_in,
                              void* d_out, int out_size, void* d_ws, size_t ws_size,
                              hipStream_t stream) {
    const float* x       = (const float*)d_in[0];
    const float* anchors = (const float*)d_in[1];
    const int*   y       = (const int*)d_in[2];
    float*       out     = (float*)d_out;

    const int n = in_sizes[2];          // N samples
    const int C = in_sizes[1] / DDIM;   // classes

    const int rowsPerSlice = 64;

    // ws layout: pseg[B*C] f32 | pcnt[B*C] u32 | sseg[nslice*C] f32 | scnt[nslice*C] f32
    long long cap = ((long long)ws_size) / ((long long)C * 8 + (long long)C * 16 / rowsPerSlice + 16);
    int B = (int)(cap < 1 ? 1 : (cap > 2048 ? 2048 : cap));
    const int nslice = (B + rowsPerSlice - 1) / rowsPerSlice;

    float*    pseg = (float*)d_ws;
    unsigned* pcnt = (unsigned*)((char*)d_ws + (size_t)B * C * 4);
    float*    sseg = (float*)((char*)d_ws + (size_t)B * C * 8);
    float*    scnt = (float*)((char*)d_ws + (size_t)B * C * 8 + (size_t)nslice * C * 4);

    const size_t ldsBytes = (size_t)C * 8;  // segL + cntL
    dist_kernel<<<B, 256, ldsBytes, stream>>>(x, anchors, y, pseg, pcnt, n, C);

    dim3 gridB((C + 255) / 256, nslice);
    reduceB_kernel<<<gridB, 256, 0, stream>>>(pseg, pcnt, sseg, scnt, B, C, rowsPerSlice);

    finalize_kernel<<<1, 1024, 0, stream>>>(sseg, scnt, out, nslice, C);
}